// Round 2
// baseline (278.785 us; speedup 1.0000x reference)
//
#include <hip/hip_runtime.h>
#include <hip/hip_bf16.h>

// GNN attention layer. V=50000, E=800000, D=H=128. Inputs f32, OUTPUT f32.
//
// R13: gru_kernel was top (57 us) with MfmaUtil 6% / VALUBusy 20% / Occ 22%.
// Occ is register-capped (~180-220 unified VGPR+AGPR: 24 resident B frags = 96
// regs live in AGPR side; reported 84 is arch-VGPR only) -> ~2 waves/SIMD, no
// TLP. Per-tile chain was serial: load ax/ac -> 24 MFMA -> 4x libm tanhf
// (branchy, ~50-100 serial instrs each). Fix is ILP: (a) fast tanh
// 1-2/(e^{2y}+1) via __expf + v_rcp, v_rcp sigmoids; (b) software-prefetch
// tile t+1's ax/ac fragments before tile t's MFMA+epilogue (same for np_hist's
// A stream). Rest = R12 (per-XCD L2-local histogram atomics, 400k scan,
// atomic-free scatter, fused conv, int2-pair aggregate).

#define V_NODES 50000
#define E_EDGES 800000
#define D_FEAT  128
#define NTILE   3125          // V/16
#define GCHUNK  5             // tiles per wave-task (625 chunks x 8 cg = 5000 waves)
#define WS_BLOCKS 1250        // 5000 waves / 4 per block

#define N8            (V_NODES * 8)   // 400000 (node,xcd) counters
#define SCAN8_BLOCKS  1563            // ceil(400000/256)
#define SCANB_CHUNKS  7               // ceil(1563/256)

typedef short bf16x8 __attribute__((ext_vector_type(8)));  // 8 bf16 in 4 VGPRs
typedef float f32x4  __attribute__((ext_vector_type(4)));
typedef unsigned short u16x4 __attribute__((ext_vector_type(4)));

// small-tensor bf16 pool element offsets
#define OFF_WEDGE 0
#define OFF_WPROJ 256
#define OFF_WIH   16640
#define OFF_WHH   65792
#define OFF_BEDGE 114944
#define OFF_BPROJ 114945
#define OFF_BIH   115073
#define OFF_BHH   115457
#define SMALL_TOTAL 115841
#define CONV_X_BLOCKS   6250   // 1.6M u16x4 / 256
#define ZERO8_BLOCKS    1563   // zero 400000 counters
#define CONV_S_BLOCKS   453
#define HIST_BLOCKS     3125   // 800000/256

// ---- device-global scratch (~51 MB; immune to ws_size) ----
__device__ int   g_is_bf16;
__device__ float g_pd[V_NODES];
__device__ float g_ps[V_NODES];
__device__ __attribute__((aligned(64))) unsigned int g_counts8[N8]; // [xcd][v]
__device__ int   g_row_off8[N8 + 1];                                // (v,xcd)-major
__device__ int   g_blocksum[SCAN8_BLOCKS];
__device__ int   g_blockoff[SCAN8_BLOCKS];
__device__ int   g_rank[E_EDGES];                                   // xcd<<24 | local rank
__device__ __attribute__((aligned(16))) int2 g_s_pair[E_EDGES];  // {src, bits(w)}
__device__ __attribute__((aligned(16))) unsigned short g_xbf[V_NODES * D_FEAT];
__device__ __attribute__((aligned(16))) unsigned short g_wsmall[SMALL_TOTAL + 15];
__device__ __attribute__((aligned(16))) unsigned short g_hv[V_NODES * D_FEAT];
__device__ __attribute__((aligned(16))) unsigned short g_ctx[V_NODES * D_FEAT];

static __device__ __forceinline__ float b2f(unsigned short u) {
  union { unsigned int i; float f; } v; v.i = ((unsigned int)u) << 16; return v.f;
}
static __device__ __forceinline__ unsigned short f2b(float f) {
  unsigned int i = __float_as_uint(f);
  unsigned int r = (i + 0x7FFFu + ((i >> 16) & 1u)) >> 16;  // RNE (NaN stays NaN)
  return (unsigned short)r;
}
static __device__ __forceinline__ bf16x8 load_frag(const unsigned short* p) {
  return *reinterpret_cast<const bf16x8*>(p);  // 16B-aligned vector load
}
static __device__ __forceinline__ float fast_rcp(float x) {
  return __builtin_amdgcn_rcpf(x);             // v_rcp_f32, ~1 ulp
}
static __device__ __forceinline__ float fast_sigmoid(float x) {
  return fast_rcp(1.f + __expf(-x));           // x<<0: exp->inf, rcp->0. ok
}
static __device__ __forceinline__ float fast_tanh(float y) {
  // 1 - 2/(e^{2y}+1); y>>0: exp->inf, rcp->0 -> 1; y<<0: exp->0 -> -1; NaN->NaN
  return 1.f - 2.f * fast_rcp(__expf(2.f * y) + 1.f);
}

// ---------------- P: dtype probe on x ----------------------------------------
__global__ void probe_kernel(const unsigned int* __restrict__ x)
{
  __shared__ int cnt;
  if (threadIdx.x == 0) cnt = 0;
  __syncthreads();
  const unsigned int w  = x[threadIdx.x];
  const unsigned int lo = w & 0xFFFFu;
  const unsigned int ex = (lo >> 7) & 0xFFu;
  if (lo != 0u && ex >= 118u && ex <= 132u) atomicAdd(&cnt, 1);
  __syncthreads();
  if (threadIdx.x == 0) g_is_bf16 = (cnt >= 200) ? 1 : 0;
}

// ---------------- C: fused convert-x | zero-counts | convert-smalls ----------
__global__ void conv_fused_kernel(
    const void* __restrict__ x,
    const void* p0, const void* p1, const void* p2, const void* p3,
    const void* p4, const void* p5, const void* p6, const void* p7)
{
  const int b = blockIdx.x;
  if (b < CONV_X_BLOCKS) {
    const int t = b * 256 + threadIdx.x;
    if (g_is_bf16) {
      reinterpret_cast<u16x4*>(g_xbf)[t] = reinterpret_cast<const u16x4*>(x)[t];
    } else {
      const float4 v = reinterpret_cast<const float4*>(x)[t];
      u16x4 o; o.x = f2b(v.x); o.y = f2b(v.y); o.z = f2b(v.z); o.w = f2b(v.w);
      reinterpret_cast<u16x4*>(g_xbf)[t] = o;
    }
  } else if (b < CONV_X_BLOCKS + ZERO8_BLOCKS) {
    const int i = (b - CONV_X_BLOCKS) * 256 + threadIdx.x;
    if (i < N8) g_counts8[i] = 0u;
  } else {
    const int i = (b - CONV_X_BLOCKS - ZERO8_BLOCKS) * 256 + threadIdx.x;
    if (i >= SMALL_TOTAL) return;
    const int offs[9] = {OFF_WEDGE, OFF_WPROJ, OFF_WIH, OFF_WHH,
                         OFF_BEDGE, OFF_BPROJ, OFF_BIH, OFF_BHH, SMALL_TOTAL};
    const void* ps[8] = {p0, p1, p2, p3, p4, p5, p6, p7};
    int r = 0;
#pragma unroll
    for (int k = 0; k < 8; k++) if (i >= offs[k]) r = k;
    const int j = i - offs[r];
    g_wsmall[i] = g_is_bf16
        ? reinterpret_cast<const unsigned short*>(ps[r])[j]
        : f2b(reinterpret_cast<const float*>(ps[r])[j]);
  }
}

// ---------------- K1: node_pre weight-stationary + hist(rank, XCD-local) -----
__global__ __launch_bounds__(256, 2) void np_hist_kernel(const int* __restrict__ dst)
{
  const int b = blockIdx.x;
  if (b >= WS_BLOCKS) {                      // ---- histogram + rank part ----
    unsigned int xcd;
    asm volatile("s_getreg_b32 %0, hwreg(HW_REG_XCC_ID, 0, 4)" : "=s"(xcd));
    xcd &= 7u;                               // L2-local slice id
    const int e = (b - WS_BLOCKS) * 256 + threadIdx.x;
    if (e < E_EDGES) {
      const int d = dst[e];
      // WORKGROUP scope -> no sc1 -> RMW executes in this XCD's TCC (shared by
      // every block of this XCD); slices are disjoint 64B-aligned regions.
      const unsigned int r = __hip_atomic_fetch_add(
          &g_counts8[xcd * V_NODES + d], 1u,
          __ATOMIC_RELAXED, __HIP_MEMORY_SCOPE_WORKGROUP);
      g_rank[e] = (int)((xcd << 24) | r);    // r < E < 2^24
    }
    return;
  }
  // ---- node_pre: wave-task g -> col-group cg, tile chunk ----
  const int g     = b * 4 + (threadIdx.x >> 6);
  const int lane  = threadIdx.x & 63;
  const int cg    = g & 7;
  const int chunk = g >> 3;                  // [0, 625)
  const int col   = lane & 15;
  const int quad  = lane >> 4;
  const int h     = 16 * cg + col;

  // resident B fragments: W_proj rows [16cg, 16cg+16)
  bf16x8 bw[4];
#pragma unroll
  for (int kk = 0; kk < 4; kk++)
    bw[kk] = load_frag(g_wsmall + OFF_WPROJ + h * D_FEAT + kk * 32 + quad * 8);
  // cg 0 also owns the edge projections (cols 0/1 of W_edge)
  bf16x8 be[4];
#pragma unroll
  for (int kk = 0; kk < 4; kk++) { be[kk] = bf16x8{0,0,0,0,0,0,0,0}; }
  if (cg == 0 && col < 2) {
#pragma unroll
    for (int kk = 0; kk < 4; kk++)
      be[kk] = load_frag(g_wsmall + OFF_WEDGE + col * D_FEAT + kk * 32 + quad * 8);
  }
  const float bp = b2f(g_wsmall[OFF_BPROJ + h]);

  const int t0 = chunk * GCHUNK;
  bf16x8 a[4];
#pragma unroll
  for (int kk = 0; kk < 4; kk++)
    a[kk] = load_frag(g_xbf + (t0 * 16 + col) * D_FEAT + kk * 32 + quad * 8);
  for (int t = t0; t < t0 + GCHUNK; t++) {
    // prefetch next tile's A while current tile computes (uniform clamp)
    const int tn = (t + 1 < t0 + GCHUNK) ? t + 1 : t;
    bf16x8 na[4];
#pragma unroll
    for (int kk = 0; kk < 4; kk++)
      na[kk] = load_frag(g_xbf + (tn * 16 + col) * D_FEAT + kk * 32 + quad * 8);
    f32x4 acc; acc[0]=0.f; acc[1]=0.f; acc[2]=0.f; acc[3]=0.f;
#pragma unroll
    for (int kk = 0; kk < 4; kk++)
      acc = __builtin_amdgcn_mfma_f32_16x16x32_bf16(a[kk], bw[kk], acc, 0, 0, 0);
#pragma unroll
    for (int r = 0; r < 4; r++)
      g_hv[(t * 16 + quad * 4 + r) * D_FEAT + h] = f2b(acc[r] + bp);
    if (cg == 0) {
      f32x4 acce; acce[0]=0.f; acce[1]=0.f; acce[2]=0.f; acce[3]=0.f;
#pragma unroll
      for (int kk = 0; kk < 4; kk++)
        acce = __builtin_amdgcn_mfma_f32_16x16x32_bf16(a[kk], be[kk], acce, 0, 0, 0);
      if (col == 0) {
#pragma unroll
        for (int r = 0; r < 4; r++) g_pd[t * 16 + quad * 4 + r] = acce[r];
      } else if (col == 1) {
#pragma unroll
        for (int r = 0; r < 4; r++) g_ps[t * 16 + quad * 4 + r] = acce[r];
      }
    }
#pragma unroll
    for (int kk = 0; kk < 4; kk++) a[kk] = na[kk];
  }
}

// ---------------- K3a: block-local exclusive scan over 400k (v,xcd)-major ----
__global__ __launch_bounds__(256) void scan_a_kernel()
{
  __shared__ int lds[256];
  const int b = blockIdx.x, t = threadIdx.x;
  const int idx = b * 256 + t;
  int v = 0;
  if (idx < N8) {
    const int node = idx >> 3, x = idx & 7;       // (v,xcd)-major <- [xcd][v]
    v = (int)g_counts8[x * V_NODES + node];
  }
  lds[t] = v;
  __syncthreads();
  for (int off = 1; off < 256; off <<= 1) {
    int tmp = (t >= off) ? lds[t - off] : 0;
    __syncthreads();
    lds[t] += tmp;
    __syncthreads();
  }
  if (idx < N8) g_row_off8[idx] = lds[t] - v;     // local exclusive prefix
  if (t == 255) g_blocksum[b] = lds[255];
}

// ---------------- K3b: scan the 1563 block totals (1 block, 7 chunks) --------
__global__ __launch_bounds__(256) void scan_b_kernel()
{
  __shared__ int lds[256];
  const int t = threadIdx.x;
  int running = 0;
  for (int c = 0; c < SCANB_CHUNKS; c++) {
    const int i = c * 256 + t;
    const int v = (i < SCAN8_BLOCKS) ? g_blocksum[i] : 0;
    lds[t] = v;
    __syncthreads();
    for (int off = 1; off < 256; off <<= 1) {
      int tmp = (t >= off) ? lds[t - off] : 0;
      __syncthreads();
      lds[t] += tmp;
      __syncthreads();
    }
    if (i < SCAN8_BLOCKS) g_blockoff[i] = running + lds[t] - v;
    running += lds[255];
    __syncthreads();                              // guard lds reuse next chunk
  }
  if (t == 0) g_row_off8[N8] = running;           // total = E
}

// ---------------- K3c: add block offsets -------------------------------------
__global__ __launch_bounds__(256) void scan_c_kernel()
{
  const int b = blockIdx.x, t = threadIdx.x;
  const int idx = b * 256 + t;
  if (idx >= N8) return;
  g_row_off8[idx] += g_blockoff[b];
}

// ---------------- K4: edge scatter — atomic-free, one 8B write/edge ----------
__global__ void edge_scatter_kernel(
    const int* __restrict__ src, const int* __restrict__ dst, int E)
{
  int e = blockIdx.x * blockDim.x + threadIdx.x;
  if (e >= E) return;
  const int d = dst[e], sn = src[e];
  float logit = g_pd[d] + g_ps[sn] + b2f(g_wsmall[OFF_BEDGE]);
  logit = (logit >= 0.f) ? logit : 0.01f * logit;           // LeakyReLU(0.01)
  const float w = __expf(logit);                            // no max-sub: cancels
  const unsigned int pr = (unsigned int)g_rank[e];
  const int pos = g_row_off8[(d << 3) + (int)(pr >> 24)] + (int)(pr & 0x00FFFFFFu);
  g_s_pair[pos] = make_int2(sn, __float_as_int(w));
}

// ---------------- K5: aggregation, 4 nodes/block (one per wave) --------------
__global__ __launch_bounds__(256) void aggregate_kernel()
{
  const int v = blockIdx.x * 4 + (threadIdx.x >> 6);   // grid 12500 -> v < 50000
  const int lane = threadIdx.x & 63;                   // lane: cols 2l, 2l+1
  const int beg = g_row_off8[v << 3], end = g_row_off8[(v << 3) + 8];
  float accx = 0.f, accy = 0.f, ssum = 0.f;
  int i = beg;
  for (; i + 4 <= end; i += 4) {       // 4 gathers in flight
    const int2 q0 = g_s_pair[i],     q1 = g_s_pair[i + 1],
               q2 = g_s_pair[i + 2], q3 = g_s_pair[i + 3];
    const float w0 = __int_as_float(q0.y), w1 = __int_as_float(q1.y),
                w2 = __int_as_float(q2.y), w3 = __int_as_float(q3.y);
    const unsigned int p0 = *reinterpret_cast<const unsigned int*>(g_hv + q0.x * D_FEAT + lane * 2);
    const unsigned int p1 = *reinterpret_cast<const unsigned int*>(g_hv + q1.x * D_FEAT + lane * 2);
    const unsigned int p2 = *reinterpret_cast<const unsigned int*>(g_hv + q2.x * D_FEAT + lane * 2);
    const unsigned int p3 = *reinterpret_cast<const unsigned int*>(g_hv + q3.x * D_FEAT + lane * 2);
    ssum += (w0 + w1) + (w2 + w3);
    accx += w0 * b2f((unsigned short)(p0 & 0xFFFFu)) + w1 * b2f((unsigned short)(p1 & 0xFFFFu))
          + w2 * b2f((unsigned short)(p2 & 0xFFFFu)) + w3 * b2f((unsigned short)(p3 & 0xFFFFu));
    accy += w0 * b2f((unsigned short)(p0 >> 16)) + w1 * b2f((unsigned short)(p1 >> 16))
          + w2 * b2f((unsigned short)(p2 >> 16)) + w3 * b2f((unsigned short)(p3 >> 16));
  }
  for (; i < end; i++) {
    const int2 q = g_s_pair[i];
    const float w = __int_as_float(q.y);
    ssum += w;
    const unsigned int pair =
        *reinterpret_cast<const unsigned int*>(g_hv + q.x * D_FEAT + lane * 2);
    accx += w * b2f((unsigned short)(pair & 0xFFFFu));
    accy += w * b2f((unsigned short)(pair >> 16));
  }
  const float inv = (end > beg) ? (1.0f / ssum) : 0.0f;     // empty segment -> c=0
  float c0 = accx * inv, c1 = accy * inv;
  c0 = (c0 > 0.f) ? c0 : (__expf(c0) - 1.f);                // elu
  c1 = (c1 > 0.f) ? c1 : (__expf(c1) - 1.f);
  const unsigned int outp = ((unsigned int)f2b(c1) << 16) | (unsigned int)f2b(c0);
  *reinterpret_cast<unsigned int*>(g_ctx + v * D_FEAT + lane * 2) = outp;
}

// ---------------- K6: GRU weight-stationary (cg per wave, stream tiles) -------
__global__ __launch_bounds__(256, 2) void gru_kernel(const float* __restrict__ xf32,
                                                     float* __restrict__ out)
{
  const int g     = blockIdx.x * 4 + (threadIdx.x >> 6);
  const int lane  = threadIdx.x & 63;
  const int cg    = g & 7;
  const int chunk = g >> 3;                  // [0, 625)
  const int col   = lane & 15;
  const int quad  = lane >> 4;
  const int h     = 16 * cg + col;
  const unsigned short* W_ih = g_wsmall + OFF_WIH;
  const unsigned short* W_hh = g_wsmall + OFF_WHH;
  const int isb = g_is_bf16;

  // per-wave constant biases for columns h
  const float br  = b2f(g_wsmall[OFF_BIH + h])       + b2f(g_wsmall[OFF_BHH + h]);
  const float bz  = b2f(g_wsmall[OFF_BIH + 128 + h]) + b2f(g_wsmall[OFF_BHH + 128 + h]);
  const float bn  = b2f(g_wsmall[OFF_BIH + 256 + h]);
  const float bh_ = b2f(g_wsmall[OFF_BHH + 256 + h]);

  // resident B fragments: 24 frags = 96 regs (unified file; launch_bounds(256,2))
  bf16x8 bIHr[4], bHHr[4], bIHz[4], bHHz[4], bIHn[4], bHHn[4];
#pragma unroll
  for (int kk = 0; kk < 4; kk++) {
    const int ko = kk * 32 + quad * 8;
    bIHr[kk] = load_frag(W_ih + h * D_FEAT + ko);
    bHHr[kk] = load_frag(W_hh + h * D_FEAT + ko);
    bIHz[kk] = load_frag(W_ih + (128 + h) * D_FEAT + ko);
    bHHz[kk] = load_frag(W_hh + (128 + h) * D_FEAT + ko);
    bIHn[kk] = load_frag(W_ih + (256 + h) * D_FEAT + ko);
    bHHn[kk] = load_frag(W_hh + (256 + h) * D_FEAT + ko);
  }

  const int t0 = chunk * GCHUNK;
  bf16x8 ax[4], ac[4];
#pragma unroll
  for (int kk = 0; kk < 4; kk++) {
    const int o = (t0 * 16 + col) * D_FEAT + kk * 32 + quad * 8;
    ax[kk] = load_frag(g_xbf + o);
    ac[kk] = load_frag(g_ctx + o);
  }
  for (int t = t0; t < t0 + GCHUNK; t++) {
    // prefetch next tile's A/C under current tile's MFMA+epilogue (uniform clamp)
    const int tn = (t + 1 < t0 + GCHUNK) ? t + 1 : t;
    bf16x8 nax[4], nac[4];
#pragma unroll
    for (int kk = 0; kk < 4; kk++) {
      const int o = (tn * 16 + col) * D_FEAT + kk * 32 + quad * 8;
      nax[kk] = load_frag(g_xbf + o);
      nac[kk] = load_frag(g_ctx + o);
    }
    f32x4 racc, zacc, niacc, nhacc;
    racc[0]=br;  racc[1]=br;  racc[2]=br;  racc[3]=br;
    zacc[0]=bz;  zacc[1]=bz;  zacc[2]=bz;  zacc[3]=bz;
    niacc[0]=bn; niacc[1]=bn; niacc[2]=bn; niacc[3]=bn;
    nhacc[0]=bh_; nhacc[1]=bh_; nhacc[2]=bh_; nhacc[3]=bh_;
#pragma unroll
    for (int kk = 0; kk < 4; kk++) {
      racc  = __builtin_amdgcn_mfma_f32_16x16x32_bf16(ac[kk], bIHr[kk], racc, 0, 0, 0);
      racc  = __builtin_amdgcn_mfma_f32_16x16x32_bf16(ax[kk], bHHr[kk], racc, 0, 0, 0);
      zacc  = __builtin_amdgcn_mfma_f32_16x16x32_bf16(ac[kk], bIHz[kk], zacc, 0, 0, 0);
      zacc  = __builtin_amdgcn_mfma_f32_16x16x32_bf16(ax[kk], bHHz[kk], zacc, 0, 0, 0);
      niacc = __builtin_amdgcn_mfma_f32_16x16x32_bf16(ac[kk], bIHn[kk], niacc, 0, 0, 0);
      nhacc = __builtin_amdgcn_mfma_f32_16x16x32_bf16(ax[kk], bHHn[kk], nhacc, 0, 0, 0);
    }
#pragma unroll
    for (int r = 0; r < 4; r++) {
      const int vrow = t * 16 + quad * 4 + r;
      const float rg = fast_sigmoid(racc[r]);
      const float zg = fast_sigmoid(zacc[r]);
      const float n  = fast_tanh(niacc[r] + rg * nhacc[r]);
      const float xv = isb ? b2f(g_xbf[vrow * D_FEAT + h]) : xf32[vrow * D_FEAT + h];
      const float hn = (1.f - zg) * n + zg * xv;
      out[vrow * D_FEAT + h] = (hn < 0.f) ? 0.f : hn;  // relu; NaN passes (canary)
    }
#pragma unroll
    for (int kk = 0; kk < 4; kk++) { ax[kk] = nax[kk]; ac[kk] = nac[kk]; }
  }
}

// ---------------- launch ------------------------------------------------------
extern "C" void kernel_launch(void* const* d_in, const int* in_sizes, int n_in,
                              void* d_out, int out_size, void* d_ws, size_t ws_size,
                              hipStream_t stream)
{
  (void)d_ws; (void)ws_size; (void)out_size;

  // resolve inputs by element count (same-size pairs keep dict order)
  int ix = -1, iWe = -1, ibe = -1, iWp = -1, ibp = -1,
      iWih = -1, iWhh = -1, ibih = -1, ibhh = -1, isrc = -1, idst = -1;
  for (int i = 0; i < n_in; i++) {
    const int s = in_sizes[i];
    if      (s == 6400000) ix = i;
    else if (s == 256)     iWe = i;
    else if (s == 1)       ibe = i;
    else if (s == 16384)   iWp = i;
    else if (s == 128)     ibp = i;
    else if (s == 49152)   { if (iWih < 0) iWih = i; else iWhh = i; }
    else if (s == 384)     { if (ibih < 0) ibih = i; else ibhh = i; }
    else if (s == 800000)  { if (isrc < 0) isrc = i; else idst = i; }
  }
  if (ix < 0 || iWe < 0 || ibe < 0 || iWp < 0 || ibp < 0 || iWih < 0 ||
      iWhh < 0 || ibih < 0 || ibhh < 0 || isrc < 0 || idst < 0) {
    ix = 0; iWe = 1; ibe = 2; iWp = 3; ibp = 4;           // dict-order fallback
    iWih = 5; iWhh = 6; ibih = 7; ibhh = 8; isrc = 9; idst = 10;
  }

  const int* src = (const int*)d_in[isrc];
  const int* dst = (const int*)d_in[idst];
  float* out = (float*)d_out;

  probe_kernel<<<1, 256, 0, stream>>>((const unsigned int*)d_in[ix]);
  conv_fused_kernel<<<CONV_X_BLOCKS + ZERO8_BLOCKS + CONV_S_BLOCKS, 256, 0, stream>>>(
      d_in[ix],
      d_in[iWe], d_in[iWp], d_in[iWih], d_in[iWhh],
      d_in[ibe], d_in[ibp], d_in[ibih], d_in[ibhh]);
  np_hist_kernel<<<WS_BLOCKS + HIST_BLOCKS, 256, 0, stream>>>(dst);
  scan_a_kernel<<<SCAN8_BLOCKS, 256, 0, stream>>>();
  scan_b_kernel<<<1, 256, 0, stream>>>();
  scan_c_kernel<<<SCAN8_BLOCKS, 256, 0, stream>>>();
  edge_scatter_kernel<<<E_EDGES / 256, 256, 0, stream>>>(src, dst, E_EDGES);
  aggregate_kernel<<<V_NODES / 4, 256, 0, stream>>>();
  gru_kernel<<<WS_BLOCKS, 256, 0, stream>>>((const float*)d_in[ix], out);
}

// Round 3
// 259.219 us; speedup vs baseline: 1.0755x; 1.0755x over previous
//
#include <hip/hip_runtime.h>
#include <hip/hip_bf16.h>

// GNN attention layer. V=50000, E=800000, D=H=128. Inputs f32, OUTPUT f32.
//
// R14: R13 post-mortem — fast-tanh halved VALUBusy (20->10%) but A-prefetch
// cost 32 regs -> Occ 22->16% -> gru 57->63 us. Kernel is latency-bound and
// wave-starved (occupancy<->duration inverse-correlated across R12/R13).
// Remaining serial stall: epilogue loaded xv per-row (4 dependent ~400cyc
// load->use chains per tile, unhidden at 2 waves/SIMD). Fix (gru only):
// (a) revert A-prefetch (restore occupancy); (b) hoist the 4 xv loads above
// the MFMA block, AFTER the 8 frag loads, so MFMAs issue at vmcnt(4) and xv
// latency hides under 24 MFMAs; (c) keep fast sigmoid/tanh. np_hist et al
// unchanged from R13.

#define V_NODES 50000
#define E_EDGES 800000
#define D_FEAT  128
#define NTILE   3125          // V/16
#define GCHUNK  5             // tiles per wave-task (625 chunks x 8 cg = 5000 waves)
#define WS_BLOCKS 1250        // 5000 waves / 4 per block

#define N8            (V_NODES * 8)   // 400000 (node,xcd) counters
#define SCAN8_BLOCKS  1563            // ceil(400000/256)
#define SCANB_CHUNKS  7               // ceil(1563/256)

typedef short bf16x8 __attribute__((ext_vector_type(8)));  // 8 bf16 in 4 VGPRs
typedef float f32x4  __attribute__((ext_vector_type(4)));
typedef unsigned short u16x4 __attribute__((ext_vector_type(4)));

// small-tensor bf16 pool element offsets
#define OFF_WEDGE 0
#define OFF_WPROJ 256
#define OFF_WIH   16640
#define OFF_WHH   65792
#define OFF_BEDGE 114944
#define OFF_BPROJ 114945
#define OFF_BIH   115073
#define OFF_BHH   115457
#define SMALL_TOTAL 115841
#define CONV_X_BLOCKS   6250   // 1.6M u16x4 / 256
#define ZERO8_BLOCKS    1563   // zero 400000 counters
#define CONV_S_BLOCKS   453
#define HIST_BLOCKS     3125   // 800000/256

// ---- device-global scratch (~51 MB; immune to ws_size) ----
__device__ int   g_is_bf16;
__device__ float g_pd[V_NODES];
__device__ float g_ps[V_NODES];
__device__ __attribute__((aligned(64))) unsigned int g_counts8[N8]; // [xcd][v]
__device__ int   g_row_off8[N8 + 1];                                // (v,xcd)-major
__device__ int   g_blocksum[SCAN8_BLOCKS];
__device__ int   g_blockoff[SCAN8_BLOCKS];
__device__ int   g_rank[E_EDGES];                                   // xcd<<24 | local rank
__device__ __attribute__((aligned(16))) int2 g_s_pair[E_EDGES];  // {src, bits(w)}
__device__ __attribute__((aligned(16))) unsigned short g_xbf[V_NODES * D_FEAT];
__device__ __attribute__((aligned(16))) unsigned short g_wsmall[SMALL_TOTAL + 15];
__device__ __attribute__((aligned(16))) unsigned short g_hv[V_NODES * D_FEAT];
__device__ __attribute__((aligned(16))) unsigned short g_ctx[V_NODES * D_FEAT];

static __device__ __forceinline__ float b2f(unsigned short u) {
  union { unsigned int i; float f; } v; v.i = ((unsigned int)u) << 16; return v.f;
}
static __device__ __forceinline__ unsigned short f2b(float f) {
  unsigned int i = __float_as_uint(f);
  unsigned int r = (i + 0x7FFFu + ((i >> 16) & 1u)) >> 16;  // RNE (NaN stays NaN)
  return (unsigned short)r;
}
static __device__ __forceinline__ bf16x8 load_frag(const unsigned short* p) {
  return *reinterpret_cast<const bf16x8*>(p);  // 16B-aligned vector load
}
static __device__ __forceinline__ float fast_rcp(float x) {
  return __builtin_amdgcn_rcpf(x);             // v_rcp_f32, ~1 ulp
}
static __device__ __forceinline__ float fast_sigmoid(float x) {
  return fast_rcp(1.f + __expf(-x));           // x<<0: exp->inf, rcp->0. ok
}
static __device__ __forceinline__ float fast_tanh(float y) {
  // 1 - 2/(e^{2y}+1); y>>0: exp->inf, rcp->0 -> 1; y<<0: exp->0 -> -1; NaN->NaN
  return 1.f - 2.f * fast_rcp(__expf(2.f * y) + 1.f);
}

// ---------------- P: dtype probe on x ----------------------------------------
__global__ void probe_kernel(const unsigned int* __restrict__ x)
{
  __shared__ int cnt;
  if (threadIdx.x == 0) cnt = 0;
  __syncthreads();
  const unsigned int w  = x[threadIdx.x];
  const unsigned int lo = w & 0xFFFFu;
  const unsigned int ex = (lo >> 7) & 0xFFu;
  if (lo != 0u && ex >= 118u && ex <= 132u) atomicAdd(&cnt, 1);
  __syncthreads();
  if (threadIdx.x == 0) g_is_bf16 = (cnt >= 200) ? 1 : 0;
}

// ---------------- C: fused convert-x | zero-counts | convert-smalls ----------
__global__ void conv_fused_kernel(
    const void* __restrict__ x,
    const void* p0, const void* p1, const void* p2, const void* p3,
    const void* p4, const void* p5, const void* p6, const void* p7)
{
  const int b = blockIdx.x;
  if (b < CONV_X_BLOCKS) {
    const int t = b * 256 + threadIdx.x;
    if (g_is_bf16) {
      reinterpret_cast<u16x4*>(g_xbf)[t] = reinterpret_cast<const u16x4*>(x)[t];
    } else {
      const float4 v = reinterpret_cast<const float4*>(x)[t];
      u16x4 o; o.x = f2b(v.x); o.y = f2b(v.y); o.z = f2b(v.z); o.w = f2b(v.w);
      reinterpret_cast<u16x4*>(g_xbf)[t] = o;
    }
  } else if (b < CONV_X_BLOCKS + ZERO8_BLOCKS) {
    const int i = (b - CONV_X_BLOCKS) * 256 + threadIdx.x;
    if (i < N8) g_counts8[i] = 0u;
  } else {
    const int i = (b - CONV_X_BLOCKS - ZERO8_BLOCKS) * 256 + threadIdx.x;
    if (i >= SMALL_TOTAL) return;
    const int offs[9] = {OFF_WEDGE, OFF_WPROJ, OFF_WIH, OFF_WHH,
                         OFF_BEDGE, OFF_BPROJ, OFF_BIH, OFF_BHH, SMALL_TOTAL};
    const void* ps[8] = {p0, p1, p2, p3, p4, p5, p6, p7};
    int r = 0;
#pragma unroll
    for (int k = 0; k < 8; k++) if (i >= offs[k]) r = k;
    const int j = i - offs[r];
    g_wsmall[i] = g_is_bf16
        ? reinterpret_cast<const unsigned short*>(ps[r])[j]
        : f2b(reinterpret_cast<const float*>(ps[r])[j]);
  }
}

// ---------------- K1: node_pre weight-stationary + hist(rank, XCD-local) -----
__global__ __launch_bounds__(256, 2) void np_hist_kernel(const int* __restrict__ dst)
{
  const int b = blockIdx.x;
  if (b >= WS_BLOCKS) {                      // ---- histogram + rank part ----
    unsigned int xcd;
    asm volatile("s_getreg_b32 %0, hwreg(HW_REG_XCC_ID, 0, 4)" : "=s"(xcd));
    xcd &= 7u;                               // L2-local slice id
    const int e = (b - WS_BLOCKS) * 256 + threadIdx.x;
    if (e < E_EDGES) {
      const int d = dst[e];
      // WORKGROUP scope -> no sc1 -> RMW executes in this XCD's TCC (shared by
      // every block of this XCD); slices are disjoint 64B-aligned regions.
      const unsigned int r = __hip_atomic_fetch_add(
          &g_counts8[xcd * V_NODES + d], 1u,
          __ATOMIC_RELAXED, __HIP_MEMORY_SCOPE_WORKGROUP);
      g_rank[e] = (int)((xcd << 24) | r);    // r < E < 2^24
    }
    return;
  }
  // ---- node_pre: wave-task g -> col-group cg, tile chunk ----
  const int g     = b * 4 + (threadIdx.x >> 6);
  const int lane  = threadIdx.x & 63;
  const int cg    = g & 7;
  const int chunk = g >> 3;                  // [0, 625)
  const int col   = lane & 15;
  const int quad  = lane >> 4;
  const int h     = 16 * cg + col;

  // resident B fragments: W_proj rows [16cg, 16cg+16)
  bf16x8 bw[4];
#pragma unroll
  for (int kk = 0; kk < 4; kk++)
    bw[kk] = load_frag(g_wsmall + OFF_WPROJ + h * D_FEAT + kk * 32 + quad * 8);
  // cg 0 also owns the edge projections (cols 0/1 of W_edge)
  bf16x8 be[4];
#pragma unroll
  for (int kk = 0; kk < 4; kk++) { be[kk] = bf16x8{0,0,0,0,0,0,0,0}; }
  if (cg == 0 && col < 2) {
#pragma unroll
    for (int kk = 0; kk < 4; kk++)
      be[kk] = load_frag(g_wsmall + OFF_WEDGE + col * D_FEAT + kk * 32 + quad * 8);
  }
  const float bp = b2f(g_wsmall[OFF_BPROJ + h]);

  const int t0 = chunk * GCHUNK;
  bf16x8 a[4];
#pragma unroll
  for (int kk = 0; kk < 4; kk++)
    a[kk] = load_frag(g_xbf + (t0 * 16 + col) * D_FEAT + kk * 32 + quad * 8);
  for (int t = t0; t < t0 + GCHUNK; t++) {
    // prefetch next tile's A while current tile computes (uniform clamp)
    const int tn = (t + 1 < t0 + GCHUNK) ? t + 1 : t;
    bf16x8 na[4];
#pragma unroll
    for (int kk = 0; kk < 4; kk++)
      na[kk] = load_frag(g_xbf + (tn * 16 + col) * D_FEAT + kk * 32 + quad * 8);
    f32x4 acc; acc[0]=0.f; acc[1]=0.f; acc[2]=0.f; acc[3]=0.f;
#pragma unroll
    for (int kk = 0; kk < 4; kk++)
      acc = __builtin_amdgcn_mfma_f32_16x16x32_bf16(a[kk], bw[kk], acc, 0, 0, 0);
#pragma unroll
    for (int r = 0; r < 4; r++)
      g_hv[(t * 16 + quad * 4 + r) * D_FEAT + h] = f2b(acc[r] + bp);
    if (cg == 0) {
      f32x4 acce; acce[0]=0.f; acce[1]=0.f; acce[2]=0.f; acce[3]=0.f;
#pragma unroll
      for (int kk = 0; kk < 4; kk++)
        acce = __builtin_amdgcn_mfma_f32_16x16x32_bf16(a[kk], be[kk], acce, 0, 0, 0);
      if (col == 0) {
#pragma unroll
        for (int r = 0; r < 4; r++) g_pd[t * 16 + quad * 4 + r] = acce[r];
      } else if (col == 1) {
#pragma unroll
        for (int r = 0; r < 4; r++) g_ps[t * 16 + quad * 4 + r] = acce[r];
      }
    }
#pragma unroll
    for (int kk = 0; kk < 4; kk++) a[kk] = na[kk];
  }
}

// ---------------- K3a: block-local exclusive scan over 400k (v,xcd)-major ----
__global__ __launch_bounds__(256) void scan_a_kernel()
{
  __shared__ int lds[256];
  const int b = blockIdx.x, t = threadIdx.x;
  const int idx = b * 256 + t;
  int v = 0;
  if (idx < N8) {
    const int node = idx >> 3, x = idx & 7;       // (v,xcd)-major <- [xcd][v]
    v = (int)g_counts8[x * V_NODES + node];
  }
  lds[t] = v;
  __syncthreads();
  for (int off = 1; off < 256; off <<= 1) {
    int tmp = (t >= off) ? lds[t - off] : 0;
    __syncthreads();
    lds[t] += tmp;
    __syncthreads();
  }
  if (idx < N8) g_row_off8[idx] = lds[t] - v;     // local exclusive prefix
  if (t == 255) g_blocksum[b] = lds[255];
}

// ---------------- K3b: scan the 1563 block totals (1 block, 7 chunks) --------
__global__ __launch_bounds__(256) void scan_b_kernel()
{
  __shared__ int lds[256];
  const int t = threadIdx.x;
  int running = 0;
  for (int c = 0; c < SCANB_CHUNKS; c++) {
    const int i = c * 256 + t;
    const int v = (i < SCAN8_BLOCKS) ? g_blocksum[i] : 0;
    lds[t] = v;
    __syncthreads();
    for (int off = 1; off < 256; off <<= 1) {
      int tmp = (t >= off) ? lds[t - off] : 0;
      __syncthreads();
      lds[t] += tmp;
      __syncthreads();
    }
    if (i < SCAN8_BLOCKS) g_blockoff[i] = running + lds[t] - v;
    running += lds[255];
    __syncthreads();                              // guard lds reuse next chunk
  }
  if (t == 0) g_row_off8[N8] = running;           // total = E
}

// ---------------- K3c: add block offsets -------------------------------------
__global__ __launch_bounds__(256) void scan_c_kernel()
{
  const int b = blockIdx.x, t = threadIdx.x;
  const int idx = b * 256 + t;
  if (idx >= N8) return;
  g_row_off8[idx] += g_blockoff[b];
}

// ---------------- K4: edge scatter — atomic-free, one 8B write/edge ----------
__global__ void edge_scatter_kernel(
    const int* __restrict__ src, const int* __restrict__ dst, int E)
{
  int e = blockIdx.x * blockDim.x + threadIdx.x;
  if (e >= E) return;
  const int d = dst[e], sn = src[e];
  float logit = g_pd[d] + g_ps[sn] + b2f(g_wsmall[OFF_BEDGE]);
  logit = (logit >= 0.f) ? logit : 0.01f * logit;           // LeakyReLU(0.01)
  const float w = __expf(logit);                            // no max-sub: cancels
  const unsigned int pr = (unsigned int)g_rank[e];
  const int pos = g_row_off8[(d << 3) + (int)(pr >> 24)] + (int)(pr & 0x00FFFFFFu);
  g_s_pair[pos] = make_int2(sn, __float_as_int(w));
}

// ---------------- K5: aggregation, 4 nodes/block (one per wave) --------------
__global__ __launch_bounds__(256) void aggregate_kernel()
{
  const int v = blockIdx.x * 4 + (threadIdx.x >> 6);   // grid 12500 -> v < 50000
  const int lane = threadIdx.x & 63;                   // lane: cols 2l, 2l+1
  const int beg = g_row_off8[v << 3], end = g_row_off8[(v << 3) + 8];
  float accx = 0.f, accy = 0.f, ssum = 0.f;
  int i = beg;
  for (; i + 4 <= end; i += 4) {       // 4 gathers in flight
    const int2 q0 = g_s_pair[i],     q1 = g_s_pair[i + 1],
               q2 = g_s_pair[i + 2], q3 = g_s_pair[i + 3];
    const float w0 = __int_as_float(q0.y), w1 = __int_as_float(q1.y),
                w2 = __int_as_float(q2.y), w3 = __int_as_float(q3.y);
    const unsigned int p0 = *reinterpret_cast<const unsigned int*>(g_hv + q0.x * D_FEAT + lane * 2);
    const unsigned int p1 = *reinterpret_cast<const unsigned int*>(g_hv + q1.x * D_FEAT + lane * 2);
    const unsigned int p2 = *reinterpret_cast<const unsigned int*>(g_hv + q2.x * D_FEAT + lane * 2);
    const unsigned int p3 = *reinterpret_cast<const unsigned int*>(g_hv + q3.x * D_FEAT + lane * 2);
    ssum += (w0 + w1) + (w2 + w3);
    accx += w0 * b2f((unsigned short)(p0 & 0xFFFFu)) + w1 * b2f((unsigned short)(p1 & 0xFFFFu))
          + w2 * b2f((unsigned short)(p2 & 0xFFFFu)) + w3 * b2f((unsigned short)(p3 & 0xFFFFu));
    accy += w0 * b2f((unsigned short)(p0 >> 16)) + w1 * b2f((unsigned short)(p1 >> 16))
          + w2 * b2f((unsigned short)(p2 >> 16)) + w3 * b2f((unsigned short)(p3 >> 16));
  }
  for (; i < end; i++) {
    const int2 q = g_s_pair[i];
    const float w = __int_as_float(q.y);
    ssum += w;
    const unsigned int pair =
        *reinterpret_cast<const unsigned int*>(g_hv + q.x * D_FEAT + lane * 2);
    accx += w * b2f((unsigned short)(pair & 0xFFFFu));
    accy += w * b2f((unsigned short)(pair >> 16));
  }
  const float inv = (end > beg) ? (1.0f / ssum) : 0.0f;     // empty segment -> c=0
  float c0 = accx * inv, c1 = accy * inv;
  c0 = (c0 > 0.f) ? c0 : (__expf(c0) - 1.f);                // elu
  c1 = (c1 > 0.f) ? c1 : (__expf(c1) - 1.f);
  const unsigned int outp = ((unsigned int)f2b(c1) << 16) | (unsigned int)f2b(c0);
  *reinterpret_cast<unsigned int*>(g_ctx + v * D_FEAT + lane * 2) = outp;
}

// ---------------- K6: GRU weight-stationary (cg per wave, stream tiles) -------
__global__ __launch_bounds__(256, 2) void gru_kernel(const float* __restrict__ xf32,
                                                     float* __restrict__ out)
{
  const int g     = blockIdx.x * 4 + (threadIdx.x >> 6);
  const int lane  = threadIdx.x & 63;
  const int cg    = g & 7;
  const int chunk = g >> 3;                  // [0, 625)
  const int col   = lane & 15;
  const int quad  = lane >> 4;
  const int h     = 16 * cg + col;
  const unsigned short* W_ih = g_wsmall + OFF_WIH;
  const unsigned short* W_hh = g_wsmall + OFF_WHH;
  const int isb = g_is_bf16;

  // per-wave constant biases for columns h
  const float br  = b2f(g_wsmall[OFF_BIH + h])       + b2f(g_wsmall[OFF_BHH + h]);
  const float bz  = b2f(g_wsmall[OFF_BIH + 128 + h]) + b2f(g_wsmall[OFF_BHH + 128 + h]);
  const float bn  = b2f(g_wsmall[OFF_BIH + 256 + h]);
  const float bh_ = b2f(g_wsmall[OFF_BHH + 256 + h]);

  // resident B fragments: 24 frags = 96 regs (unified file; launch_bounds(256,2))
  bf16x8 bIHr[4], bHHr[4], bIHz[4], bHHz[4], bIHn[4], bHHn[4];
#pragma unroll
  for (int kk = 0; kk < 4; kk++) {
    const int ko = kk * 32 + quad * 8;
    bIHr[kk] = load_frag(W_ih + h * D_FEAT + ko);
    bHHr[kk] = load_frag(W_hh + h * D_FEAT + ko);
    bIHz[kk] = load_frag(W_ih + (128 + h) * D_FEAT + ko);
    bHHz[kk] = load_frag(W_hh + (128 + h) * D_FEAT + ko);
    bIHn[kk] = load_frag(W_ih + (256 + h) * D_FEAT + ko);
    bHHn[kk] = load_frag(W_hh + (256 + h) * D_FEAT + ko);
  }

  const int t0 = chunk * GCHUNK;
  for (int t = t0; t < t0 + GCHUNK; t++) {
    const int arow = t * 16 + col;
    bf16x8 ax[4], ac[4];
#pragma unroll
    for (int kk = 0; kk < 4; kk++) {
      const int o = arow * D_FEAT + kk * 32 + quad * 8;
      ax[kk] = load_frag(g_xbf + o);
      ac[kk] = load_frag(g_ctx + o);
    }
    // hoist xv loads (issued AFTER the 8 frag loads -> MFMAs start at vmcnt(4),
    // xv latency hides under the 24-MFMA block instead of heading each row)
    float xv[4];
    if (isb) {
#pragma unroll
      for (int r = 0; r < 4; r++)
        xv[r] = b2f(g_xbf[(t * 16 + quad * 4 + r) * D_FEAT + h]);
    } else {
#pragma unroll
      for (int r = 0; r < 4; r++)
        xv[r] = xf32[(t * 16 + quad * 4 + r) * D_FEAT + h];
    }
    f32x4 racc, zacc, niacc, nhacc;
    racc[0]=br;  racc[1]=br;  racc[2]=br;  racc[3]=br;
    zacc[0]=bz;  zacc[1]=bz;  zacc[2]=bz;  zacc[3]=bz;
    niacc[0]=bn; niacc[1]=bn; niacc[2]=bn; niacc[3]=bn;
    nhacc[0]=bh_; nhacc[1]=bh_; nhacc[2]=bh_; nhacc[3]=bh_;
#pragma unroll
    for (int kk = 0; kk < 4; kk++) {
      racc  = __builtin_amdgcn_mfma_f32_16x16x32_bf16(ac[kk], bIHr[kk], racc, 0, 0, 0);
      racc  = __builtin_amdgcn_mfma_f32_16x16x32_bf16(ax[kk], bHHr[kk], racc, 0, 0, 0);
      zacc  = __builtin_amdgcn_mfma_f32_16x16x32_bf16(ac[kk], bIHz[kk], zacc, 0, 0, 0);
      zacc  = __builtin_amdgcn_mfma_f32_16x16x32_bf16(ax[kk], bHHz[kk], zacc, 0, 0, 0);
      niacc = __builtin_amdgcn_mfma_f32_16x16x32_bf16(ac[kk], bIHn[kk], niacc, 0, 0, 0);
      nhacc = __builtin_amdgcn_mfma_f32_16x16x32_bf16(ax[kk], bHHn[kk], nhacc, 0, 0, 0);
    }
#pragma unroll
    for (int r = 0; r < 4; r++) {
      const int vrow = t * 16 + quad * 4 + r;
      const float rg = fast_sigmoid(racc[r]);
      const float zg = fast_sigmoid(zacc[r]);
      const float n  = fast_tanh(niacc[r] + rg * nhacc[r]);
      const float hn = (1.f - zg) * n + zg * xv[r];
      out[vrow * D_FEAT + h] = (hn < 0.f) ? 0.f : hn;  // relu; NaN passes (canary)
    }
  }
}

// ---------------- launch ------------------------------------------------------
extern "C" void kernel_launch(void* const* d_in, const int* in_sizes, int n_in,
                              void* d_out, int out_size, void* d_ws, size_t ws_size,
                              hipStream_t stream)
{
  (void)d_ws; (void)ws_size; (void)out_size;

  // resolve inputs by element count (same-size pairs keep dict order)
  int ix = -1, iWe = -1, ibe = -1, iWp = -1, ibp = -1,
      iWih = -1, iWhh = -1, ibih = -1, ibhh = -1, isrc = -1, idst = -1;
  for (int i = 0; i < n_in; i++) {
    const int s = in_sizes[i];
    if      (s == 6400000) ix = i;
    else if (s == 256)     iWe = i;
    else if (s == 1)       ibe = i;
    else if (s == 16384)   iWp = i;
    else if (s == 128)     ibp = i;
    else if (s == 49152)   { if (iWih < 0) iWih = i; else iWhh = i; }
    else if (s == 384)     { if (ibih < 0) ibih = i; else ibhh = i; }
    else if (s == 800000)  { if (isrc < 0) isrc = i; else idst = i; }
  }
  if (ix < 0 || iWe < 0 || ibe < 0 || iWp < 0 || ibp < 0 || iWih < 0 ||
      iWhh < 0 || ibih < 0 || ibhh < 0 || isrc < 0 || idst < 0) {
    ix = 0; iWe = 1; ibe = 2; iWp = 3; ibp = 4;           // dict-order fallback
    iWih = 5; iWhh = 6; ibih = 7; ibhh = 8; isrc = 9; idst = 10;
  }

  const int* src = (const int*)d_in[isrc];
  const int* dst = (const int*)d_in[idst];
  float* out = (float*)d_out;

  probe_kernel<<<1, 256, 0, stream>>>((const unsigned int*)d_in[ix]);
  conv_fused_kernel<<<CONV_X_BLOCKS + ZERO8_BLOCKS + CONV_S_BLOCKS, 256, 0, stream>>>(
      d_in[ix],
      d_in[iWe], d_in[iWp], d_in[iWih], d_in[iWhh],
      d_in[ibe], d_in[ibp], d_in[ibih], d_in[ibhh]);
  np_hist_kernel<<<WS_BLOCKS + HIST_BLOCKS, 256, 0, stream>>>(dst);
  scan_a_kernel<<<SCAN8_BLOCKS, 256, 0, stream>>>();
  scan_b_kernel<<<1, 256, 0, stream>>>();
  scan_c_kernel<<<SCAN8_BLOCKS, 256, 0, stream>>>();
  edge_scatter_kernel<<<E_EDGES / 256, 256, 0, stream>>>(src, dst, E_EDGES);
  aggregate_kernel<<<V_NODES / 4, 256, 0, stream>>>();
  gru_kernel<<<WS_BLOCKS, 256, 0, stream>>>((const float*)d_in[ix], out);
}